// Round 5
// baseline (251.942 us; speedup 1.0000x reference)
//
#include <hip/hip_runtime.h>
#include <math.h>

namespace {

constexpr int B  = 16;
constexpr int S  = 1024;
constexpr int H  = 768;
constexpr int NH = 12;
constexpr int DH = 64;
constexpr int FF = 3072;
constexpr int XSPL = 32;       // xbar k-splits (one per 32-key score tile)
constexpr float EPS = 1e-12f;

__device__ __forceinline__ float waveReduceSum(float v) {
#pragma unroll
    for (int d = 1; d < 64; d <<= 1) v += __shfl_xor(v, d);
    return v;
}

__device__ __forceinline__ float blockReduceSum768(float v, float* red) {
    const int lane = threadIdx.x & 63;
    const int wid  = threadIdx.x >> 6;
    v = waveReduceSum(v);
    __syncthreads();
    if (lane == 0) red[wid] = v;
    __syncthreads();
    float s = 0.f;
#pragma unroll
    for (int w = 0; w < 12; ++w) s += red[w];
    return s;
}

// ---------------------------------------------------------------------------
// split-K partial GEMM over the 16 CLS rows:
//   part[sp][b][j] = sum_{i in split sp} A[b,i] * W[i,j]
// grid (N/64, ISPL), block 256 = 64 j-lanes x 4 b-groups
// ---------------------------------------------------------------------------
template <int K, int ISPL, int N>
__global__ __launch_bounds__(256) void gemm_partial(
        const float* __restrict__ A, int lda, int jtOfsA,
        const float* __restrict__ W, float* __restrict__ part) {
    constexpr int IR = K / ISPL;
    __shared__ float Asl[B * IR];
    const int jt  = blockIdx.x;
    const int sp  = blockIdx.y;
    const int i0  = sp * IR;
    const int tid = threadIdx.x;

    for (int e = tid; e < B * IR; e += 256) {
        const int b = e / IR, ii = e % IR;
        Asl[e] = A[(size_t)b * lda + (size_t)jt * jtOfsA + i0 + ii];
    }
    __syncthreads();

    const int jl = tid & 63;
    const int bg = tid >> 6;
    const int j  = jt * 64 + jl;
    const float* wp_ = W + (size_t)i0 * N + j;
    const float* a0 = Asl + (bg * 4 + 0) * IR;
    const float* a1 = Asl + (bg * 4 + 1) * IR;
    const float* a2 = Asl + (bg * 4 + 2) * IR;
    const float* a3 = Asl + (bg * 4 + 3) * IR;
    float acc0 = 0.f, acc1 = 0.f, acc2 = 0.f, acc3 = 0.f;
#pragma unroll
    for (int ii = 0; ii < IR; ++ii) {
        const float w = wp_[(size_t)ii * N];
        acc0 += w * a0[ii];
        acc1 += w * a1[ii];
        acc2 += w * a2[ii];
        acc3 += w * a3[ii];
    }
    float* pp = part + ((size_t)sp * B) * N + j;
    pp[(size_t)(bg * 4 + 0) * N] = acc0;
    pp[(size_t)(bg * 4 + 1) * N] = acc1;
    pp[(size_t)(bg * 4 + 2) * N] = acc2;
    pp[(size_t)(bg * 4 + 3) * N] = acc3;
}

// A is itself a split-K partial set: A[b,i] = bias[i] + sum_sp2 Ain[sp2][b][i]
template <int K, int ISPL, int N, int RED>
__global__ __launch_bounds__(256) void gemm_partial_red(
        const float* __restrict__ Ain, const float* __restrict__ bias,
        const float* __restrict__ W, float* __restrict__ part) {
    constexpr int IR = K / ISPL;
    __shared__ float Asl[B * IR];
    const int jt  = blockIdx.x;
    const int sp  = blockIdx.y;
    const int i0  = sp * IR;
    const int tid = threadIdx.x;

    for (int e = tid; e < B * IR; e += 256) {
        const int b = e / IR, ii = e % IR;
        float v = bias[i0 + ii];
#pragma unroll
        for (int sp2 = 0; sp2 < RED; ++sp2)
            v += Ain[((size_t)sp2 * B + b) * K + i0 + ii];
        Asl[e] = v;
    }
    __syncthreads();

    const int jl = tid & 63;
    const int bg = tid >> 6;
    const int j  = jt * 64 + jl;
    const float* wp_ = W + (size_t)i0 * N + j;
    const float* a0 = Asl + (bg * 4 + 0) * IR;
    const float* a1 = Asl + (bg * 4 + 1) * IR;
    const float* a2 = Asl + (bg * 4 + 2) * IR;
    const float* a3 = Asl + (bg * 4 + 3) * IR;
    float acc0 = 0.f, acc1 = 0.f, acc2 = 0.f, acc3 = 0.f;
#pragma unroll
    for (int ii = 0; ii < IR; ++ii) {
        const float w = wp_[(size_t)ii * N];
        acc0 += w * a0[ii];
        acc1 += w * a1[ii];
        acc2 += w * a2[ii];
        acc3 += w * a3[ii];
    }
    float* pp = part + ((size_t)sp * B) * N + j;
    pp[(size_t)(bg * 4 + 0) * N] = acc0;
    pp[(size_t)(bg * 4 + 1) * N] = acc1;
    pp[(size_t)(bg * 4 + 2) * N] = acc2;
    pp[(size_t)(bg * 4 + 3) * N] = acc3;
}

// Same but staging applies exact GELU: Asl = gelu(bias + sum parts)
template <int K, int ISPL, int N, int RED>
__global__ __launch_bounds__(256) void gemm_partial_red_gelu(
        const float* __restrict__ Ain, const float* __restrict__ bias,
        const float* __restrict__ W, float* __restrict__ part) {
    constexpr int IR = K / ISPL;
    __shared__ float Asl[B * IR];
    const int jt  = blockIdx.x;
    const int sp  = blockIdx.y;
    const int i0  = sp * IR;
    const int tid = threadIdx.x;

    for (int e = tid; e < B * IR; e += 256) {
        const int b = e / IR, ii = e % IR;
        float v = bias[i0 + ii];
#pragma unroll
        for (int sp2 = 0; sp2 < RED; ++sp2)
            v += Ain[((size_t)sp2 * B + b) * K + i0 + ii];
        Asl[e] = 0.5f * v * (1.0f + erff(v * 0.70710678118654752440f));
    }
    __syncthreads();

    const int jl = tid & 63;
    const int bg = tid >> 6;
    const int j  = jt * 64 + jl;
    const float* wp_ = W + (size_t)i0 * N + j;
    const float* a0 = Asl + (bg * 4 + 0) * IR;
    const float* a1 = Asl + (bg * 4 + 1) * IR;
    const float* a2 = Asl + (bg * 4 + 2) * IR;
    const float* a3 = Asl + (bg * 4 + 3) * IR;
    float acc0 = 0.f, acc1 = 0.f, acc2 = 0.f, acc3 = 0.f;
#pragma unroll 32
    for (int ii = 0; ii < IR; ++ii) {
        const float w = wp_[(size_t)ii * N];
        acc0 += w * a0[ii];
        acc1 += w * a1[ii];
        acc2 += w * a2[ii];
        acc3 += w * a3[ii];
    }
    float* pp = part + ((size_t)sp * B) * N + j;
    pp[(size_t)(bg * 4 + 0) * N] = acc0;
    pp[(size_t)(bg * 4 + 1) * N] = acc1;
    pp[(size_t)(bg * 4 + 2) * N] = acc2;
    pp[(size_t)(bg * 4 + 3) * N] = acc3;
}

// u[b,h,i] = sum_d wk[i, h*64+d] * q0[b, h*64+d]; weights read exactly once.
// q0 is reduced inline from q0_part (+bq). constk[b,h] = bk_h . q0_h (seg 0).
// grid (NH, 12), block 256 = 64 i-lanes x 4 b-groups
__global__ __launch_bounds__(256) void u_kernel3(
        const float* __restrict__ q0_part, const float* __restrict__ bq,
        const float* __restrict__ wk, const float* __restrict__ bk,
        float* __restrict__ u, float* __restrict__ constk) {
    const int h = blockIdx.x, seg = blockIdx.y;
    const int i0 = seg * 64;
    __shared__ float qh[B][DH + 1];     // +1 pad: spread banks
    __shared__ float wkl[64][DH + 1];   // +1 pad: avoid 32-way conflict
    const int tid = threadIdx.x;

    for (int e = tid; e < B * DH; e += 256) {
        const int b = e >> 6, d = e & 63;
        float v = bq[h * DH + d];
#pragma unroll
        for (int sp = 0; sp < 24; ++sp)
            v += q0_part[((size_t)sp * B + b) * H + h * DH + d];
        qh[b][d] = v;
    }
    {
        const float4* wg = (const float4*)(wk + (size_t)i0 * H + h * DH);
        for (int e = tid; e < 64 * 16; e += 256) {
            const int r = e >> 4, c4 = e & 15;
            const float4 w = wg[(size_t)r * (H / 4) + c4];
            wkl[r][c4 * 4 + 0] = w.x;
            wkl[r][c4 * 4 + 1] = w.y;
            wkl[r][c4 * 4 + 2] = w.z;
            wkl[r][c4 * 4 + 3] = w.w;
        }
    }
    __syncthreads();

    if (seg == 0 && tid < B) {
        float s = 0.f;
#pragma unroll
        for (int d = 0; d < DH; ++d) s += bk[h * DH + d] * qh[tid][d];
        constk[tid * NH + h] = s;
    }

    const int il = tid & 63;
    const int bg = tid >> 6;
    float acc0 = 0.f, acc1 = 0.f, acc2 = 0.f, acc3 = 0.f;
#pragma unroll
    for (int d = 0; d < DH; ++d) {
        const float w = wkl[il][d];
        acc0 += w * qh[bg * 4 + 0][d];
        acc1 += w * qh[bg * 4 + 1][d];
        acc2 += w * qh[bg * 4 + 2][d];
        acc3 += w * qh[bg * 4 + 3][d];
    }
    u[((size_t)((bg * 4 + 0) * NH + h)) * H + i0 + il] = acc0;
    u[((size_t)((bg * 4 + 1) * NH + h)) * H + i0 + il] = acc1;
    u[((size_t)((bg * 4 + 2) * NH + h)) * H + i0 + il] = acc2;
    u[((size_t)((bg * 4 + 3) * NH + h)) * H + i0 + il] = acc3;
}

// ctx partials with fused 32-way xbar-partial reduction AND softmax rinv:
//   A[b,i] = rinv[b,jt] * sum_s2 xpart[((b*32+s2)*NH + jt)*H + i]
template <int ISPL>
__global__ __launch_bounds__(256) void gemm_xpart(
        const float* __restrict__ xpart, const float* __restrict__ psum,
        const float* __restrict__ W, float* __restrict__ part) {
    constexpr int IR = H / ISPL;
    __shared__ float Asl[B * IR];
    __shared__ float rinvl[B];
    const int jt  = blockIdx.x;       // head
    const int sp  = blockIdx.y;
    const int i0  = sp * IR;
    const int tid = threadIdx.x;

    if (tid < B) {
        float s = 0.f;
#pragma unroll
        for (int kt = 0; kt < XSPL; ++kt)
            s += psum[((size_t)(tid * XSPL + kt)) * NH + jt];
        rinvl[tid] = 1.0f / s;
    }
    __syncthreads();

    for (int e = tid; e < B * IR; e += 256) {
        const int bb = e / IR, ii = e % IR;
        float v = 0.f;
#pragma unroll
        for (int s2 = 0; s2 < XSPL; ++s2)
            v += xpart[(((size_t)(bb * XSPL + s2)) * NH + jt) * H + i0 + ii];
        Asl[e] = v * rinvl[bb];
    }
    __syncthreads();

    const int jl = tid & 63;
    const int bg = tid >> 6;
    const int j  = jt * 64 + jl;
    const float* wp_ = W + (size_t)i0 * H + j;
    const float* a0 = Asl + (bg * 4 + 0) * IR;
    const float* a1 = Asl + (bg * 4 + 1) * IR;
    const float* a2 = Asl + (bg * 4 + 2) * IR;
    const float* a3 = Asl + (bg * 4 + 3) * IR;
    float acc0 = 0.f, acc1 = 0.f, acc2 = 0.f, acc3 = 0.f;
#pragma unroll
    for (int ii = 0; ii < IR; ++ii) {
        const float w = wp_[(size_t)ii * H];
        acc0 += w * a0[ii];
        acc1 += w * a1[ii];
        acc2 += w * a2[ii];
        acc3 += w * a3[ii];
    }
    float* pp = part + ((size_t)sp * B) * H + j;
    pp[(size_t)(bg * 4 + 0) * H] = acc0;
    pp[(size_t)(bg * 4 + 1) * H] = acc1;
    pp[(size_t)(bg * 4 + 2) * H] = acc2;
    pp[(size_t)(bg * 4 + 3) * H] = acc3;
}

// Fused score + xbar partial (verified rounds 1/4):
//   e[k,h] = exp( x[b,k]·u[b,h]/8 + constk + mask )   (kept in LDS only)
//   psum[b][kt][h] = sum of e over this block's 32 k's
//   xpart[b][kt][h][j] = sum_{k in tile} e[k,h] * x[b,k,j]   (UN-normalized)
// grid (B, S/32), block 256
__global__ __launch_bounds__(256, 2) void score_xbar_kernel(
        const float* __restrict__ x, const float* __restrict__ u,
        const float* __restrict__ constk, const float* __restrict__ mask,
        float* __restrict__ psum, float* __restrict__ xpart) {
    const int b  = blockIdx.x;
    const int kt = blockIdx.y;
    __shared__ __align__(16) float ul[NH * H];
    __shared__ float ck[NH];
    __shared__ float wsum[4][NH];
    __shared__ __align__(16) float el[32][NH];
    const int tid = threadIdx.x;
    {
        const float4* ug = (const float4*)(u + (size_t)b * NH * H);
        float4* ul4 = (float4*)ul;
        for (int e = tid; e < NH * H / 4; e += 256) ul4[e] = ug[e];
        if (tid < NH) ck[tid] = constk[b * NH + tid];
    }
    __syncthreads();

    const int jj = tid & 15, kk = tid >> 4;
    const int k0 = kt * 32 + kk * 2;
    float4 xv0[12], xv1[12];
    {
        const float4* xr0 = (const float4*)(x + ((size_t)b * S + k0) * H);
        const float4* xr1 = (const float4*)(x + ((size_t)b * S + k0 + 1) * H);
#pragma unroll
        for (int t = 0; t < 12; ++t) { xv0[t] = xr0[jj + 16 * t]; xv1[t] = xr1[jj + 16 * t]; }
    }
    const float4* ul4 = (const float4*)ul;
    float acc0[NH], acc1[NH];
#pragma unroll
    for (int h = 0; h < NH; ++h) {
        float a0 = 0.f, a1 = 0.f;
#pragma unroll
        for (int t = 0; t < 12; ++t) {
            const float4 uv = ul4[h * 192 + jj + 16 * t];
            a0 += xv0[t].x * uv.x + xv0[t].y * uv.y + xv0[t].z * uv.z + xv0[t].w * uv.w;
            a1 += xv1[t].x * uv.x + xv1[t].y * uv.y + xv1[t].z * uv.z + xv1[t].w * uv.w;
        }
        acc0[h] = a0; acc1[h] = a1;
    }
#pragma unroll
    for (int h = 0; h < NH; ++h) {
#pragma unroll
        for (int d = 1; d < 16; d <<= 1) {
            acc0[h] += __shfl_xor(acc0[h], d);
            acc1[h] += __shfl_xor(acc1[h], d);
        }
    }
    const float mk0 = mask[b * S + k0];
    const float mk1 = mask[b * S + k0 + 1];
    float e0[NH], e1[NH], ps[NH];
#pragma unroll
    for (int h = 0; h < NH; ++h) {
        e0[h] = expf(acc0[h] * 0.125f + ck[h] + mk0);
        e1[h] = expf(acc1[h] * 0.125f + ck[h] + mk1);
        ps[h] = e0[h] + e1[h];
    }
    if (jj == 0) {
#pragma unroll
        for (int h = 0; h < NH; ++h) {
            el[kk * 2 + 0][h] = e0[h];
            el[kk * 2 + 1][h] = e1[h];
        }
    }
#pragma unroll
    for (int h = 0; h < NH; ++h) {
        ps[h] += __shfl_xor(ps[h], 16);
        ps[h] += __shfl_xor(ps[h], 32);
    }
    const int wid = tid >> 6;
    if ((tid & 63) == 0) {
#pragma unroll
        for (int h = 0; h < NH; ++h) wsum[wid][h] = ps[h];
    }
    __syncthreads();   // publishes el[][] AND wsum[][]
    if (tid < NH)
        psum[((size_t)(b * XSPL + kt)) * NH + tid] =
            wsum[0][tid] + wsum[1][tid] + wsum[2][tid] + wsum[3][tid];

    // phase 2: xbar partials; x rows L1/L2-hot (just read above)
    float accx[3][NH];
#pragma unroll
    for (int c = 0; c < 3; ++c)
#pragma unroll
        for (int h = 0; h < NH; ++h) accx[c][h] = 0.f;
    const float* xb = x + ((size_t)b * S + (size_t)kt * 32) * H;
#pragma unroll 4
    for (int k = 0; k < 32; ++k) {
        const float xs0 = xb[(size_t)k * H + tid];
        const float xs1 = xb[(size_t)k * H + tid + 256];
        const float xs2 = xb[(size_t)k * H + tid + 512];
        const float4 ea = *(const float4*)(&el[k][0]);
        const float4 eb = *(const float4*)(&el[k][4]);
        const float4 ec = *(const float4*)(&el[k][8]);
        const float eh[12] = {ea.x, ea.y, ea.z, ea.w,
                              eb.x, eb.y, eb.z, eb.w,
                              ec.x, ec.y, ec.z, ec.w};
#pragma unroll
        for (int h = 0; h < NH; ++h) {
            accx[0][h] += eh[h] * xs0;
            accx[1][h] += eh[h] * xs1;
            accx[2][h] += eh[h] * xs2;
        }
    }
    float* op = xpart + ((size_t)(b * XSPL + kt)) * NH * H + tid;
#pragma unroll
    for (int h = 0; h < NH; ++h) {
        op[(size_t)h * H +   0] = accx[0][h];
        op[(size_t)h * H + 256] = accx[1][h];
        op[(size_t)h * H + 512] = accx[2][h];
    }
}

// out[b,:] = LayerNorm( sum_sp part + bias + resid ) * g + beta
template <int ISPL>
__global__ __launch_bounds__(768) void ln_kernel(
        const float* __restrict__ part, const float* __restrict__ bias,
        const float* __restrict__ resid, int residStride,
        const float* __restrict__ g, const float* __restrict__ bet,
        float* __restrict__ out) {
    __shared__ float red[12];
    const int b = blockIdx.x, j = threadIdx.x;
    float v = bias[j] + resid[(size_t)b * residStride + j];
#pragma unroll
    for (int sp = 0; sp < ISPL; ++sp) v += part[((size_t)sp * B + b) * H + j];
    const float mu = blockReduceSum768(v, red) * (1.0f / H);
    const float d  = v - mu;
    const float var = blockReduceSum768(d * d, red) * (1.0f / H);
    out[(size_t)b * H + j] = d * rsqrtf(var + EPS) * g[j] + bet[j];
}

// Fused pooler + classifier:
//   pooled[b,j] = tanh(hidden[b,:]·wp[:,j] + bp[j]);  out[b] = pooled·wm + bm
// grid B, block 768 (one j per thread); wp walked coalesced, hidden in LDS
__global__ __launch_bounds__(768) void poolcls_kernel(
        const float* __restrict__ hidden, const float* __restrict__ wp,
        const float* __restrict__ bp, const float* __restrict__ wm,
        const float* __restrict__ bm, float* __restrict__ out) {
    __shared__ float hl[H];
    __shared__ float red[12];
    const int b = blockIdx.x, j = threadIdx.x;
    hl[j] = hidden[(size_t)b * H + j];
    __syncthreads();
    float acc = bp[j];
#pragma unroll 8
    for (int i = 0; i < H; ++i)
        acc += hl[i] * wp[(size_t)i * H + j];
    const float v = tanhf(acc);
    const float s = blockReduceSum768(v * wm[j], red);
    if (j == 0) out[b] = s + bm[0];
}

} // namespace

extern "C" void kernel_launch(void* const* d_in, const int* in_sizes, int n_in,
                              void* d_out, int out_size, void* d_ws, size_t ws_size,
                              hipStream_t stream) {
    const float* x    = (const float*)d_in[0];
    const float* mask = (const float*)d_in[1];
    const float* wq   = (const float*)d_in[2];
    const float* bq   = (const float*)d_in[3];
    const float* wk   = (const float*)d_in[4];
    const float* bk   = (const float*)d_in[5];
    const float* wv   = (const float*)d_in[6];
    const float* bv   = (const float*)d_in[7];
    const float* wo   = (const float*)d_in[8];
    const float* bo   = (const float*)d_in[9];
    const float* ln1g = (const float*)d_in[10];
    const float* ln1b = (const float*)d_in[11];
    const float* w1   = (const float*)d_in[12];
    const float* b1   = (const float*)d_in[13];
    const float* w2   = (const float*)d_in[14];
    const float* b2   = (const float*)d_in[15];
    const float* ln2g = (const float*)d_in[16];
    const float* ln2b = (const float*)d_in[17];
    const float* wp   = (const float*)d_in[18];
    const float* bp   = (const float*)d_in[19];
    const float* wm   = (const float*)d_in[20];
    const float* bm   = (const float*)d_in[21];
    float* out = (float*)d_out;

    // -------- workspace (lifetime-overlapped arena; ~24 MB) --------
    float* ws = (float*)d_ws;
    size_t o = 0;
    float* u        = ws + o; o += (size_t)B * NH * H;      // 147456
    float* constk   = ws + o; o += 256;
    float* psum     = ws + o; o += (size_t)B * XSPL * NH;   // 6144
    float* attn_out = ws + o; o += (size_t)B * H;
    float* hidden   = ws + o; o += (size_t)B * H;
    float* arena    = ws + o;
    // arena aliases (sequential lifetimes):
    float* q0_part   = arena;                                  // 24*B*H, dies after u_kernel3
    float* xpart     = arena;                                  // XSPL*B*NH*H = 4718592
    float* ctx_part  = arena + (size_t)XSPL * B * NH * H;      // 24*B*H (reads xpart)
    float* wo_part   = ctx_part + (size_t)24 * B * H;          // 24*B*H (reads ctx_part)
    float* ffn1_part = arena;                                  // 24*B*FF (xpart dead)
    float* ffn2_part = arena + (size_t)24 * B * FF;            // 48*B*H (reads ffn1_part)
    (void)ws_size; (void)in_sizes; (void)n_in; (void)out_size;

    // 1) q0 partials = x[:,0,:] @ wq  (weights read once)
    gemm_partial<H, 24, H><<<dim3(12, 24), 256, 0, stream>>>(x, S * H, 0, wq, q0_part);
    // 2) u = wk_head @ q0_head (fused q0 reduce + bq; weights once); constk
    u_kernel3<<<dim3(NH, 12), 256, 0, stream>>>(q0_part, bq, wk, bk, u, constk);
    // 3) score + xbar fused (x read once from HBM; phase-2 re-read cache-hot)
    score_xbar_kernel<<<dim3(B, S / 32), 256, 0, stream>>>(x, u, constk, mask, psum, xpart);
    // 4) ctx partials: per-head xbar slice @ wv (fused 32-way reduce + rinv)
    gemm_xpart<24><<<dim3(12, 24), 256, 0, stream>>>(xpart, psum, wv, ctx_part);
    // 5) wo GEMM (fused ctx reduce + bv); LN1 with residual x[:,0,:]
    gemm_partial_red<H, 24, H, 24><<<dim3(12, 24), 256, 0, stream>>>(ctx_part, bv, wo, wo_part);
    ln_kernel<24><<<B, 768, 0, stream>>>(wo_part, bo, x, S * H, ln1g, ln1b, attn_out);
    // 6) FFN (gelu fused into ffn2 staging)
    gemm_partial<H, 24, FF><<<dim3(48, 24), 256, 0, stream>>>(attn_out, H, 0, w1, ffn1_part);
    gemm_partial_red_gelu<FF, 48, H, 24><<<dim3(12, 48), 256, 0, stream>>>(ffn1_part, b1, w2, ffn2_part);
    ln_kernel<48><<<B, 768, 0, stream>>>(ffn2_part, b2, attn_out, H, ln2g, ln2b, hidden);
    // 7) pooler + classifier fused
    poolcls_kernel<<<B, 768, 0, stream>>>(hidden, wp, bp, wm, bm, out);
}

// Round 6
// 212.942 us; speedup vs baseline: 1.1831x; 1.1831x over previous
//
#include <hip/hip_runtime.h>
#include <math.h>

namespace {

constexpr int B  = 16;
constexpr int S  = 1024;
constexpr int H  = 768;
constexpr int NH = 12;
constexpr int DH = 64;
constexpr int FF = 3072;
constexpr int XSPL = 32;       // xbar k-splits (one per 32-key score tile)
constexpr float EPS = 1e-12f;

__device__ __forceinline__ float waveReduceSum(float v) {
#pragma unroll
    for (int d = 1; d < 64; d <<= 1) v += __shfl_xor(v, d);
    return v;
}

__device__ __forceinline__ float blockReduceSum768(float v, float* red) {
    const int lane = threadIdx.x & 63;
    const int wid  = threadIdx.x >> 6;
    v = waveReduceSum(v);
    __syncthreads();
    if (lane == 0) red[wid] = v;
    __syncthreads();
    float s = 0.f;
#pragma unroll
    for (int w = 0; w < 12; ++w) s += red[w];
    return s;
}

// ---------------------------------------------------------------------------
// split-K partial GEMM over the 16 CLS rows:
//   part[sp][b][j] = sum_{i in split sp} A[b,i] * W[i,j]
// grid (N/64, ISPL), block 256 = 64 j-lanes x 4 b-groups
// ---------------------------------------------------------------------------
template <int K, int ISPL, int N>
__global__ __launch_bounds__(256) void gemm_partial(
        const float* __restrict__ A, int lda, int jtOfsA,
        const float* __restrict__ W, float* __restrict__ part) {
    constexpr int IR = K / ISPL;
    __shared__ float Asl[B * IR];
    const int jt  = blockIdx.x;
    const int sp  = blockIdx.y;
    const int i0  = sp * IR;
    const int tid = threadIdx.x;

    for (int e = tid; e < B * IR; e += 256) {
        const int b = e / IR, ii = e % IR;
        Asl[e] = A[(size_t)b * lda + (size_t)jt * jtOfsA + i0 + ii];
    }
    __syncthreads();

    const int jl = tid & 63;
    const int bg = tid >> 6;
    const int j  = jt * 64 + jl;
    const float* wp_ = W + (size_t)i0 * N + j;
    const float* a0 = Asl + (bg * 4 + 0) * IR;
    const float* a1 = Asl + (bg * 4 + 1) * IR;
    const float* a2 = Asl + (bg * 4 + 2) * IR;
    const float* a3 = Asl + (bg * 4 + 3) * IR;
    float acc0 = 0.f, acc1 = 0.f, acc2 = 0.f, acc3 = 0.f;
#pragma unroll
    for (int ii = 0; ii < IR; ++ii) {
        const float w = wp_[(size_t)ii * N];
        acc0 += w * a0[ii];
        acc1 += w * a1[ii];
        acc2 += w * a2[ii];
        acc3 += w * a3[ii];
    }
    float* pp = part + ((size_t)sp * B) * N + j;
    pp[(size_t)(bg * 4 + 0) * N] = acc0;
    pp[(size_t)(bg * 4 + 1) * N] = acc1;
    pp[(size_t)(bg * 4 + 2) * N] = acc2;
    pp[(size_t)(bg * 4 + 3) * N] = acc3;
}

// A is itself a split-K partial set: A[b,i] = bias[i] + sum_sp2 Ain[sp2][b][i]
template <int K, int ISPL, int N, int RED>
__global__ __launch_bounds__(256) void gemm_partial_red(
        const float* __restrict__ Ain, const float* __restrict__ bias,
        const float* __restrict__ W, float* __restrict__ part) {
    constexpr int IR = K / ISPL;
    __shared__ float Asl[B * IR];
    const int jt  = blockIdx.x;
    const int sp  = blockIdx.y;
    const int i0  = sp * IR;
    const int tid = threadIdx.x;

    for (int e = tid; e < B * IR; e += 256) {
        const int b = e / IR, ii = e % IR;
        float v = bias[i0 + ii];
#pragma unroll
        for (int sp2 = 0; sp2 < RED; ++sp2)
            v += Ain[((size_t)sp2 * B + b) * K + i0 + ii];
        Asl[e] = v;
    }
    __syncthreads();

    const int jl = tid & 63;
    const int bg = tid >> 6;
    const int j  = jt * 64 + jl;
    const float* wp_ = W + (size_t)i0 * N + j;
    const float* a0 = Asl + (bg * 4 + 0) * IR;
    const float* a1 = Asl + (bg * 4 + 1) * IR;
    const float* a2 = Asl + (bg * 4 + 2) * IR;
    const float* a3 = Asl + (bg * 4 + 3) * IR;
    float acc0 = 0.f, acc1 = 0.f, acc2 = 0.f, acc3 = 0.f;
#pragma unroll
    for (int ii = 0; ii < IR; ++ii) {
        const float w = wp_[(size_t)ii * N];
        acc0 += w * a0[ii];
        acc1 += w * a1[ii];
        acc2 += w * a2[ii];
        acc3 += w * a3[ii];
    }
    float* pp = part + ((size_t)sp * B) * N + j;
    pp[(size_t)(bg * 4 + 0) * N] = acc0;
    pp[(size_t)(bg * 4 + 1) * N] = acc1;
    pp[(size_t)(bg * 4 + 2) * N] = acc2;
    pp[(size_t)(bg * 4 + 3) * N] = acc3;
}

// Same but staging applies exact GELU: Asl = gelu(bias + sum parts)
template <int K, int ISPL, int N, int RED>
__global__ __launch_bounds__(256) void gemm_partial_red_gelu(
        const float* __restrict__ Ain, const float* __restrict__ bias,
        const float* __restrict__ W, float* __restrict__ part) {
    constexpr int IR = K / ISPL;
    __shared__ float Asl[B * IR];
    const int jt  = blockIdx.x;
    const int sp  = blockIdx.y;
    const int i0  = sp * IR;
    const int tid = threadIdx.x;

    for (int e = tid; e < B * IR; e += 256) {
        const int b = e / IR, ii = e % IR;
        float v = bias[i0 + ii];
#pragma unroll
        for (int sp2 = 0; sp2 < RED; ++sp2)
            v += Ain[((size_t)sp2 * B + b) * K + i0 + ii];
        Asl[e] = 0.5f * v * (1.0f + erff(v * 0.70710678118654752440f));
    }
    __syncthreads();

    const int jl = tid & 63;
    const int bg = tid >> 6;
    const int j  = jt * 64 + jl;
    const float* wp_ = W + (size_t)i0 * N + j;
    const float* a0 = Asl + (bg * 4 + 0) * IR;
    const float* a1 = Asl + (bg * 4 + 1) * IR;
    const float* a2 = Asl + (bg * 4 + 2) * IR;
    const float* a3 = Asl + (bg * 4 + 3) * IR;
    float acc0 = 0.f, acc1 = 0.f, acc2 = 0.f, acc3 = 0.f;
#pragma unroll 32
    for (int ii = 0; ii < IR; ++ii) {
        const float w = wp_[(size_t)ii * N];
        acc0 += w * a0[ii];
        acc1 += w * a1[ii];
        acc2 += w * a2[ii];
        acc3 += w * a3[ii];
    }
    float* pp = part + ((size_t)sp * B) * N + j;
    pp[(size_t)(bg * 4 + 0) * N] = acc0;
    pp[(size_t)(bg * 4 + 1) * N] = acc1;
    pp[(size_t)(bg * 4 + 2) * N] = acc2;
    pp[(size_t)(bg * 4 + 3) * N] = acc3;
}

// u[b,h,i] = sum_d wk[i, h*64+d] * q0[b, h*64+d]; weights read exactly once.
// q0 is reduced inline from q0_part (+bq). constk[b,h] = bk_h . q0_h (seg 0).
// grid (NH, 12), block 256 = 64 i-lanes x 4 b-groups
__global__ __launch_bounds__(256) void u_kernel3(
        const float* __restrict__ q0_part, const float* __restrict__ bq,
        const float* __restrict__ wk, const float* __restrict__ bk,
        float* __restrict__ u, float* __restrict__ constk) {
    const int h = blockIdx.x, seg = blockIdx.y;
    const int i0 = seg * 64;
    __shared__ float qh[B][DH + 1];     // +1 pad: spread banks
    __shared__ float wkl[64][DH + 1];   // +1 pad: avoid 32-way conflict
    const int tid = threadIdx.x;

    for (int e = tid; e < B * DH; e += 256) {
        const int b = e >> 6, d = e & 63;
        float v = bq[h * DH + d];
#pragma unroll
        for (int sp = 0; sp < 24; ++sp)
            v += q0_part[((size_t)sp * B + b) * H + h * DH + d];
        qh[b][d] = v;
    }
    {
        const float4* wg = (const float4*)(wk + (size_t)i0 * H + h * DH);
        for (int e = tid; e < 64 * 16; e += 256) {
            const int r = e >> 4, c4 = e & 15;
            const float4 w = wg[(size_t)r * (H / 4) + c4];
            wkl[r][c4 * 4 + 0] = w.x;
            wkl[r][c4 * 4 + 1] = w.y;
            wkl[r][c4 * 4 + 2] = w.z;
            wkl[r][c4 * 4 + 3] = w.w;
        }
    }
    __syncthreads();

    if (seg == 0 && tid < B) {
        float s = 0.f;
#pragma unroll
        for (int d = 0; d < DH; ++d) s += bk[h * DH + d] * qh[tid][d];
        constk[tid * NH + h] = s;
    }

    const int il = tid & 63;
    const int bg = tid >> 6;
    float acc0 = 0.f, acc1 = 0.f, acc2 = 0.f, acc3 = 0.f;
#pragma unroll
    for (int d = 0; d < DH; ++d) {
        const float w = wkl[il][d];
        acc0 += w * qh[bg * 4 + 0][d];
        acc1 += w * qh[bg * 4 + 1][d];
        acc2 += w * qh[bg * 4 + 2][d];
        acc3 += w * qh[bg * 4 + 3][d];
    }
    u[((size_t)((bg * 4 + 0) * NH + h)) * H + i0 + il] = acc0;
    u[((size_t)((bg * 4 + 1) * NH + h)) * H + i0 + il] = acc1;
    u[((size_t)((bg * 4 + 2) * NH + h)) * H + i0 + il] = acc2;
    u[((size_t)((bg * 4 + 3) * NH + h)) * H + i0 + il] = acc3;
}

// ctx partials with fused 32-way xbar-partial reduction AND softmax rinv:
//   A[b,i] = rinv[b,jt] * sum_s2 xpart[((b*32+s2)*NH + jt)*H + i]
template <int ISPL>
__global__ __launch_bounds__(256) void gemm_xpart(
        const float* __restrict__ xpart, const float* __restrict__ psum,
        const float* __restrict__ W, float* __restrict__ part) {
    constexpr int IR = H / ISPL;
    __shared__ float Asl[B * IR];
    __shared__ float rinvl[B];
    const int jt  = blockIdx.x;       // head
    const int sp  = blockIdx.y;
    const int i0  = sp * IR;
    const int tid = threadIdx.x;

    if (tid < B) {
        float s = 0.f;
#pragma unroll
        for (int kt = 0; kt < XSPL; ++kt)
            s += psum[((size_t)(tid * XSPL + kt)) * NH + jt];
        rinvl[tid] = 1.0f / s;
    }
    __syncthreads();

    for (int e = tid; e < B * IR; e += 256) {
        const int bb = e / IR, ii = e % IR;
        float v = 0.f;
#pragma unroll
        for (int s2 = 0; s2 < XSPL; ++s2)
            v += xpart[(((size_t)(bb * XSPL + s2)) * NH + jt) * H + i0 + ii];
        Asl[e] = v * rinvl[bb];
    }
    __syncthreads();

    const int jl = tid & 63;
    const int bg = tid >> 6;
    const int j  = jt * 64 + jl;
    const float* wp_ = W + (size_t)i0 * H + j;
    const float* a0 = Asl + (bg * 4 + 0) * IR;
    const float* a1 = Asl + (bg * 4 + 1) * IR;
    const float* a2 = Asl + (bg * 4 + 2) * IR;
    const float* a3 = Asl + (bg * 4 + 3) * IR;
    float acc0 = 0.f, acc1 = 0.f, acc2 = 0.f, acc3 = 0.f;
#pragma unroll
    for (int ii = 0; ii < IR; ++ii) {
        const float w = wp_[(size_t)ii * H];
        acc0 += w * a0[ii];
        acc1 += w * a1[ii];
        acc2 += w * a2[ii];
        acc3 += w * a3[ii];
    }
    float* pp = part + ((size_t)sp * B) * H + j;
    pp[(size_t)(bg * 4 + 0) * H] = acc0;
    pp[(size_t)(bg * 4 + 1) * H] = acc1;
    pp[(size_t)(bg * 4 + 2) * H] = acc2;
    pp[(size_t)(bg * 4 + 3) * H] = acc3;
}

// Fused score + xbar partial (verified rounds 1/4/5):
//   e[k,h] = exp( x[b,k]·u[b,h]/8 + constk + mask )   (kept in LDS only)
//   psum[b][kt][h] = sum of e over this block's 32 k's
//   xpart[b][kt][h][j] = sum_{k in tile} e[k,h] * x[b,k,j]   (UN-normalized)
// grid (B, S/32), block 256
__global__ __launch_bounds__(256, 2) void score_xbar_kernel(
        const float* __restrict__ x, const float* __restrict__ u,
        const float* __restrict__ constk, const float* __restrict__ mask,
        float* __restrict__ psum, float* __restrict__ xpart) {
    const int b  = blockIdx.x;
    const int kt = blockIdx.y;
    __shared__ __align__(16) float ul[NH * H];
    __shared__ float ck[NH];
    __shared__ float wsum[4][NH];
    __shared__ __align__(16) float el[32][NH];
    const int tid = threadIdx.x;
    {
        const float4* ug = (const float4*)(u + (size_t)b * NH * H);
        float4* ul4 = (float4*)ul;
        for (int e = tid; e < NH * H / 4; e += 256) ul4[e] = ug[e];
        if (tid < NH) ck[tid] = constk[b * NH + tid];
    }
    __syncthreads();

    const int jj = tid & 15, kk = tid >> 4;
    const int k0 = kt * 32 + kk * 2;
    float4 xv0[12], xv1[12];
    {
        const float4* xr0 = (const float4*)(x + ((size_t)b * S + k0) * H);
        const float4* xr1 = (const float4*)(x + ((size_t)b * S + k0 + 1) * H);
#pragma unroll
        for (int t = 0; t < 12; ++t) { xv0[t] = xr0[jj + 16 * t]; xv1[t] = xr1[jj + 16 * t]; }
    }
    const float4* ul4 = (const float4*)ul;
    float acc0[NH], acc1[NH];
#pragma unroll
    for (int h = 0; h < NH; ++h) {
        float a0 = 0.f, a1 = 0.f;
#pragma unroll
        for (int t = 0; t < 12; ++t) {
            const float4 uv = ul4[h * 192 + jj + 16 * t];
            a0 += xv0[t].x * uv.x + xv0[t].y * uv.y + xv0[t].z * uv.z + xv0[t].w * uv.w;
            a1 += xv1[t].x * uv.x + xv1[t].y * uv.y + xv1[t].z * uv.z + xv1[t].w * uv.w;
        }
        acc0[h] = a0; acc1[h] = a1;
    }
#pragma unroll
    for (int h = 0; h < NH; ++h) {
#pragma unroll
        for (int d = 1; d < 16; d <<= 1) {
            acc0[h] += __shfl_xor(acc0[h], d);
            acc1[h] += __shfl_xor(acc1[h], d);
        }
    }
    const float mk0 = mask[b * S + k0];
    const float mk1 = mask[b * S + k0 + 1];
    float e0[NH], e1[NH], ps[NH];
#pragma unroll
    for (int h = 0; h < NH; ++h) {
        e0[h] = expf(acc0[h] * 0.125f + ck[h] + mk0);
        e1[h] = expf(acc1[h] * 0.125f + ck[h] + mk1);
        ps[h] = e0[h] + e1[h];
    }
    if (jj == 0) {
#pragma unroll
        for (int h = 0; h < NH; ++h) {
            el[kk * 2 + 0][h] = e0[h];
            el[kk * 2 + 1][h] = e1[h];
        }
    }
#pragma unroll
    for (int h = 0; h < NH; ++h) {
        ps[h] += __shfl_xor(ps[h], 16);
        ps[h] += __shfl_xor(ps[h], 32);
    }
    const int wid = tid >> 6;
    if ((tid & 63) == 0) {
#pragma unroll
        for (int h = 0; h < NH; ++h) wsum[wid][h] = ps[h];
    }
    __syncthreads();   // publishes el[][] AND wsum[][]
    if (tid < NH)
        psum[((size_t)(b * XSPL + kt)) * NH + tid] =
            wsum[0][tid] + wsum[1][tid] + wsum[2][tid] + wsum[3][tid];

    // phase 2: xbar partials; x rows L1/L2-hot (just read above)
    float accx[3][NH];
#pragma unroll
    for (int c = 0; c < 3; ++c)
#pragma unroll
        for (int h = 0; h < NH; ++h) accx[c][h] = 0.f;
    const float* xb = x + ((size_t)b * S + (size_t)kt * 32) * H;
#pragma unroll 4
    for (int k = 0; k < 32; ++k) {
        const float xs0 = xb[(size_t)k * H + tid];
        const float xs1 = xb[(size_t)k * H + tid + 256];
        const float xs2 = xb[(size_t)k * H + tid + 512];
        const float4 ea = *(const float4*)(&el[k][0]);
        const float4 eb = *(const float4*)(&el[k][4]);
        const float4 ec = *(const float4*)(&el[k][8]);
        const float eh[12] = {ea.x, ea.y, ea.z, ea.w,
                              eb.x, eb.y, eb.z, eb.w,
                              ec.x, ec.y, ec.z, ec.w};
#pragma unroll
        for (int h = 0; h < NH; ++h) {
            accx[0][h] += eh[h] * xs0;
            accx[1][h] += eh[h] * xs1;
            accx[2][h] += eh[h] * xs2;
        }
    }
    float* op = xpart + ((size_t)(b * XSPL + kt)) * NH * H + tid;
#pragma unroll
    for (int h = 0; h < NH; ++h) {
        op[(size_t)h * H +   0] = accx[0][h];
        op[(size_t)h * H + 256] = accx[1][h];
        op[(size_t)h * H + 512] = accx[2][h];
    }
}

// out[b,:] = LayerNorm( sum_sp part + bias + resid ) * g + beta
template <int ISPL>
__global__ __launch_bounds__(768) void ln_kernel(
        const float* __restrict__ part, const float* __restrict__ bias,
        const float* __restrict__ resid, int residStride,
        const float* __restrict__ g, const float* __restrict__ bet,
        float* __restrict__ out) {
    __shared__ float red[12];
    const int b = blockIdx.x, j = threadIdx.x;
    float v = bias[j] + resid[(size_t)b * residStride + j];
#pragma unroll
    for (int sp = 0; sp < ISPL; ++sp) v += part[((size_t)sp * B + b) * H + j];
    const float mu = blockReduceSum768(v, red) * (1.0f / H);
    const float d  = v - mu;
    const float var = blockReduceSum768(d * d, red) * (1.0f / H);
    out[(size_t)b * H + j] = d * rsqrtf(var + EPS) * g[j] + bet[j];
}

// pooled = tanh(sum_sp part + bp); cls[b] = pooled . wm + bm
template <int ISPL>
__global__ __launch_bounds__(768) void cls_kernel(
        const float* __restrict__ part, const float* __restrict__ bp,
        const float* __restrict__ wm, const float* __restrict__ bm,
        float* __restrict__ out) {
    __shared__ float red[12];
    const int b = blockIdx.x, j = threadIdx.x;
    float v = bp[j];
#pragma unroll
    for (int sp = 0; sp < ISPL; ++sp) v += part[((size_t)sp * B + b) * H + j];
    v = tanhf(v);
    const float s = blockReduceSum768(v * wm[j], red);
    if (j == 0) out[b] = s + bm[0];
}

} // namespace

extern "C" void kernel_launch(void* const* d_in, const int* in_sizes, int n_in,
                              void* d_out, int out_size, void* d_ws, size_t ws_size,
                              hipStream_t stream) {
    const float* x    = (const float*)d_in[0];
    const float* mask = (const float*)d_in[1];
    const float* wq   = (const float*)d_in[2];
    const float* bq   = (const float*)d_in[3];
    const float* wk   = (const float*)d_in[4];
    const float* bk   = (const float*)d_in[5];
    const float* wv   = (const float*)d_in[6];
    const float* bv   = (const float*)d_in[7];
    const float* wo   = (const float*)d_in[8];
    const float* bo   = (const float*)d_in[9];
    const float* ln1g = (const float*)d_in[10];
    const float* ln1b = (const float*)d_in[11];
    const float* w1   = (const float*)d_in[12];
    const float* b1   = (const float*)d_in[13];
    const float* w2   = (const float*)d_in[14];
    const float* b2   = (const float*)d_in[15];
    const float* ln2g = (const float*)d_in[16];
    const float* ln2b = (const float*)d_in[17];
    const float* wp   = (const float*)d_in[18];
    const float* bp   = (const float*)d_in[19];
    const float* wm   = (const float*)d_in[20];
    const float* bm   = (const float*)d_in[21];
    float* out = (float*)d_out;

    // -------- workspace (lifetime-overlapped arena; ~24 MB) --------
    float* ws = (float*)d_ws;
    size_t o = 0;
    float* u        = ws + o; o += (size_t)B * NH * H;      // 147456
    float* constk   = ws + o; o += 256;
    float* psum     = ws + o; o += (size_t)B * XSPL * NH;   // 6144
    float* attn_out = ws + o; o += (size_t)B * H;
    float* hidden   = ws + o; o += (size_t)B * H;
    float* arena    = ws + o;
    // arena aliases (sequential lifetimes):
    float* q0_part   = arena;                                  // 24*B*H, dies after u_kernel3
    float* xpart     = arena;                                  // XSPL*B*NH*H = 4718592
    float* ctx_part  = arena + (size_t)XSPL * B * NH * H;      // 24*B*H (reads xpart)
    float* wo_part   = ctx_part + (size_t)24 * B * H;          // 24*B*H (reads ctx_part)
    float* ffn1_part = arena;                                  // 24*B*FF (xpart dead)
    float* ffn2_part = arena + (size_t)24 * B * FF;            // 48*B*H (reads ffn1_part)
    float* pool_part = arena;                                  // 24*B*H (ffn1 dead)
    (void)ws_size; (void)in_sizes; (void)n_in; (void)out_size;

    // 1) q0 partials = x[:,0,:] @ wq  (weights read once)
    gemm_partial<H, 24, H><<<dim3(12, 24), 256, 0, stream>>>(x, S * H, 0, wq, q0_part);
    // 2) u = wk_head @ q0_head (fused q0 reduce + bq; weights once); constk
    u_kernel3<<<dim3(NH, 12), 256, 0, stream>>>(q0_part, bq, wk, bk, u, constk);
    // 3) score + xbar fused (x read once from HBM; phase-2 re-read cache-hot)
    score_xbar_kernel<<<dim3(B, S / 32), 256, 0, stream>>>(x, u, constk, mask, psum, xpart);
    // 4) ctx partials: per-head xbar slice @ wv (fused 32-way reduce + rinv)
    gemm_xpart<24><<<dim3(12, 24), 256, 0, stream>>>(xpart, psum, wv, ctx_part);
    // 5) wo GEMM (fused ctx reduce + bv); LN1 with residual x[:,0,:]
    gemm_partial_red<H, 24, H, 24><<<dim3(12, 24), 256, 0, stream>>>(ctx_part, bv, wo, wo_part);
    ln_kernel<24><<<B, 768, 0, stream>>>(wo_part, bo, x, S * H, ln1g, ln1b, attn_out);
    // 6) FFN (gelu fused into ffn2 staging)
    gemm_partial<H, 24, FF><<<dim3(48, 24), 256, 0, stream>>>(attn_out, H, 0, w1, ffn1_part);
    gemm_partial_red_gelu<FF, 48, H, 24><<<dim3(12, 48), 256, 0, stream>>>(ffn1_part, b1, w2, ffn2_part);
    ln_kernel<48><<<B, 768, 0, stream>>>(ffn2_part, b2, attn_out, H, ln2g, ln2b, hidden);
    // 7) pooler GEMM (288 blocks — parallelism-preserving) + classifier
    gemm_partial<H, 24, H><<<dim3(12, 24), 256, 0, stream>>>(hidden, H, 0, wp, pool_part);
    cls_kernel<24><<<B, 768, 0, stream>>>(pool_part, bp, wm, bm, out);
}